// Round 3
// baseline (284.691 us; speedup 1.0000x reference)
//
#include <hip/hip_runtime.h>
#include <math.h>

#define NN   1024
#define HIDD 256
#define NH   8
#define NW   32   // 1024 bits / 32 per word
#define MC   128  // flash m-chunk size
#define NCH  8    // flash chunks
#define GS   130  // geo2 row stride (dwords) — quad banks 0/8/16/24, 2-way free
#define PSW  136  // Pb row stride (shorts)

typedef __attribute__((ext_vector_type(8))) short short8;
typedef __attribute__((ext_vector_type(4))) float f32x4;

__device__ __forceinline__ float silu_f(float x) {
    // x * sigmoid(x); v_rcp instead of full-precision div chain (~1ulp rel err)
    return x * __builtin_amdgcn_rcpf(1.0f + __expf(-x));
}
__device__ __forceinline__ unsigned short f2bf(float x) {
    unsigned b = __float_as_uint(x);
    return (unsigned short)((b + 0x7FFFu + ((b >> 16) & 1u)) >> 16);
}
__device__ __forceinline__ float bf2f(unsigned u) {
    return __uint_as_float(u << 16);
}

// ---------------- fused prep ----------------
// b <  256 : feature f32->bf16 conversion, 8 elems/thread, vectorized
// b < 1024 : weight transposes (QKVO 256, gate W1 512)
// b == 1024: topo 2-entry table (path bit 0/1)
// b == 1025/1026: geo MLP table — 512 knots over dist in [0,16], bf16 packed
// b >= 1027: edge scatter -> row bitsets

__global__ __launch_bounds__(256)
void prep_kernel(const float* __restrict__ src, const float* __restrict__ tgt,
                 const float* __restrict__ Wq, const float* __restrict__ Wk,
                 const float* __restrict__ Wv, const float* __restrict__ Wo,
                 const float* __restrict__ gaw1,
                 const float* __restrict__ tw1, const float* __restrict__ tb1,
                 const float* __restrict__ tw2, const float* __restrict__ tb2,
                 const float* __restrict__ gw1, const float* __restrict__ gb1,
                 const float* __restrict__ gw2, const float* __restrict__ gb2,
                 const int* __restrict__ ei, int E,
                 unsigned short* __restrict__ src_bf, unsigned short* __restrict__ tgt_bf,
                 unsigned short* __restrict__ gateA,
                 unsigned short* __restrict__ WqT, unsigned short* __restrict__ WkT,
                 unsigned short* __restrict__ WvT, unsigned short* __restrict__ WoT,
                 unsigned short* __restrict__ gaw1T,
                 float* __restrict__ t01, unsigned* __restrict__ gtab,
                 unsigned* __restrict__ prow) {
    __shared__ float tile[32][33];
    int b = blockIdx.x, t = threadIdx.x;
    if (b < 256) {
        int idx = b * 256 + t;          // 65536 threads, 8 elems each
        int n = idx >> 6, g = idx & 63;
        int j = g * 8;
        const float* base = (g < 32) ? (src + n * 256 + j)
                                     : (tgt + n * 256 + j - 256);
        float4 v0 = *(const float4*)base;
        float4 v1 = *(const float4*)(base + 4);
        unsigned short u[8] = {f2bf(v0.x), f2bf(v0.y), f2bf(v0.z), f2bf(v0.w),
                               f2bf(v1.x), f2bf(v1.y), f2bf(v1.z), f2bf(v1.w)};
        int4 pk = *(int4*)u;
        *(int4*)&gateA[n * 512 + j] = pk;
        if (g < 32) *(int4*)&src_bf[n * 256 + j] = pk;
        else        *(int4*)&tgt_bf[n * 256 + j - 256] = pk;
    } else if (b < 1024) {
        int b2 = b - 256;
        const float* W; unsigned short* Wt; int Kd, Nd, n0, k0;
        if (b2 < 256) {
            int which = b2 >> 6, tl = b2 & 63;
            W  = (which == 0) ? Wq : (which == 1) ? Wk : (which == 2) ? Wv : Wo;
            Wt = (which == 0) ? WqT : (which == 1) ? WkT : (which == 2) ? WvT : WoT;
            Kd = 256; Nd = 256;
            n0 = (tl & 7) * 32; k0 = (tl >> 3) * 32;
        } else {
            int b3 = b2 - 256;
            W = gaw1; Wt = gaw1T; Kd = 512; Nd = 1024;
            n0 = (b3 & 31) * 32; k0 = (b3 >> 5) * 32;
        }
        int tx = t & 31, ty = t >> 5;
        #pragma unroll
        for (int p = 0; p < 4; ++p)
            tile[ty + p * 8][tx] = W[(k0 + ty + p * 8) * (long)Nd + n0 + tx];
        __syncthreads();
        #pragma unroll
        for (int p = 0; p < 4; ++p)
            Wt[(n0 + ty + p * 8) * (long)Kd + k0 + tx] = f2bf(tile[tx][ty + p * 8]);
    } else if (b == 1024) {
        if (t < 16) {
            int h = t & 7;
            float x = (t >> 3) ? 1.0f : 0.0f;
            float acc = tb2[h];
            for (int c = 0; c < 32; ++c)
                acc += silu_f(x * tw1[c] + tb1[c]) * tw2[c * 8 + h];
            t01[t] = acc;
        }
    } else if (b == 1025 || b == 1026) {
        int e = (b - 1025) * 256 + t;   // knot 0..511, dist = e/32
        float d = (float)e * 0.03125f;
        float go[8];
        #pragma unroll
        for (int h = 0; h < 8; ++h) go[h] = gb2[h];
        for (int c = 0; c < 32; ++c) {
            float hh = silu_f(d * gw1[c] + gb1[c]);
            #pragma unroll
            for (int h = 0; h < 8; ++h) go[h] += hh * gw2[c * 8 + h];
        }
        #pragma unroll
        for (int h2 = 0; h2 < 4; ++h2)
            gtab[e * 4 + h2] = (unsigned)f2bf(go[2 * h2]) |
                               ((unsigned)f2bf(go[2 * h2 + 1]) << 16);
    } else {
        int e = (b - 1027) * 256 + t;
        if (e < E) {
            int r = ei[e], c = ei[E + e];
            if ((unsigned)r < NN && (unsigned)c < NN)
                atomicOr(&prow[r * NW + (c >> 5)], 1u << (c & 31));
        }
    }
}

// ---------------- path propagation: 3 iters in ONE kernel (grid barrier) ----
// 256 blocks (<= 256 CUs, nothing else concurrent -> co-residency guaranteed).
// Device-scope fences + agent atomics per G16 (cross-XCD L2 non-coherence).

__device__ __forceinline__ unsigned path_row_gather(const unsigned* __restrict__ pin,
                                                    const unsigned* __restrict__ arow,
                                                    int i, int wj) {
    unsigned inw = pin[i * NW + wj];
    unsigned acc = 0u;
    for (int w2 = 0; w2 < NW; ++w2) {
        unsigned m = __shfl(inw, w2, 64);   // wave-uniform word
        while (m) {
            int bb = __ffs(m) - 1;
            m &= m - 1;
            acc |= arow[(((w2 << 5) | bb)) * NW + wj];
        }
    }
    return inw & acc;
}

__device__ __forceinline__ void gsync(unsigned* bar, unsigned target) {
    __threadfence();                    // release: flush this block's writes
    __syncthreads();
    if (threadIdx.x == 0) {
        __hip_atomic_fetch_add(bar, 1u, __ATOMIC_RELEASE, __HIP_MEMORY_SCOPE_AGENT);
        while (__hip_atomic_load(bar, __ATOMIC_ACQUIRE, __HIP_MEMORY_SCOPE_AGENT) < target)
            __builtin_amdgcn_s_sleep(2);
    }
    __syncthreads();
    __threadfence();                    // acquire: see remote writes
}

__global__ __launch_bounds__(256)
void path3_kernel(const unsigned* __restrict__ arow,   // adjacency (preserved)
                  unsigned* __restrict__ p1, unsigned* __restrict__ p2,
                  unsigned* __restrict__ bar) {
    int t  = threadIdx.x;
    int l  = t & 63;
    int wj = l & 31;
    int i  = blockIdx.x * 4 + (t >> 6);
    unsigned r1 = path_row_gather(arow, arow, i, wj);
    if (l < 32) p1[i * NW + wj] = r1;
    gsync(bar, 256);
    unsigned r2 = path_row_gather(p1, arow, i, wj);
    if (l < 32) p2[i * NW + wj] = r2;
    gsync(bar, 512);
    unsigned r3 = path_row_gather(p2, arow, i, wj);
    if (l < 32) p1[i * NW + wj] = r3;   // final path in p1
}

// ---------------- shared MFMA 64x64 tile (register-prefetch pipeline) -------

__device__ __forceinline__ void mfma_tile64(const unsigned short* __restrict__ A,
                                            const unsigned short* __restrict__ Bt,
                                            int K, int i0, int j0, int t,
                                            f32x4 acc[2][2],
                                            unsigned short* As, unsigned short* Bs) {
    int l = t & 63, w = t >> 6;
    int wi = w >> 1, wj = w & 1;
    int quad = l >> 4, lj = l & 15;
    int sr = t >> 2, skp = (t & 3) * 8;
    f32x4 z = {0.f, 0.f, 0.f, 0.f};
    acc[0][0] = z; acc[0][1] = z; acc[1][0] = z; acc[1][1] = z;
    const unsigned short* pa = &A[(i0 + sr) * (long)K + skp];
    const unsigned short* pb = &Bt[(j0 + sr) * (long)K + skp];
    int4 ra = *(const int4*)pa;
    int4 rb = *(const int4*)pb;
    for (int k0 = 0; k0 < K; k0 += 32) {
        *(int4*)&As[sr * 32 + skp] = ra;
        *(int4*)&Bs[sr * 32 + skp] = rb;
        __syncthreads();
        if (k0 + 32 < K) {              // prefetch next tile; hides under MFMAs
            ra = *(const int4*)(pa + k0 + 32);
            rb = *(const int4*)(pb + k0 + 32);
        }
        short8 a0 = *(short8*)&As[(wi * 32 + lj) * 32 + quad * 8];
        short8 a1 = *(short8*)&As[(wi * 32 + 16 + lj) * 32 + quad * 8];
        short8 b0 = *(short8*)&Bs[(wj * 32 + lj) * 32 + quad * 8];
        short8 b1 = *(short8*)&Bs[(wj * 32 + 16 + lj) * 32 + quad * 8];
        acc[0][0] = __builtin_amdgcn_mfma_f32_16x16x32_bf16(a0, b0, acc[0][0], 0, 0, 0);
        acc[0][1] = __builtin_amdgcn_mfma_f32_16x16x32_bf16(a0, b1, acc[0][1], 0, 0, 0);
        acc[1][0] = __builtin_amdgcn_mfma_f32_16x16x32_bf16(a1, b0, acc[1][0], 0, 0, 0);
        acc[1][1] = __builtin_amdgcn_mfma_f32_16x16x32_bf16(a1, b1, acc[1][1], 0, 0, 0);
        __syncthreads();
    }
}

// ---------------- projections: QKV (192) + gate hidden w/ fused logits (256) --

__global__ __launch_bounds__(256)
void proj_kernel(const unsigned short* __restrict__ src_bf,
                 const unsigned short* __restrict__ tgt_bf,
                 const unsigned short* __restrict__ gateA,
                 const unsigned short* __restrict__ WqT,
                 const unsigned short* __restrict__ WkT,
                 const unsigned short* __restrict__ WvT,
                 const unsigned short* __restrict__ gaw1T,
                 const float* __restrict__ bq, const float* __restrict__ bk,
                 const float* __restrict__ bv, const float* __restrict__ gab1,
                 const float* __restrict__ gaw2,
                 unsigned short* __restrict__ q_bf, unsigned short* __restrict__ k_bf,
                 unsigned short* __restrict__ vT, float* __restrict__ glog) {
    __shared__ unsigned short As[64 * 32];
    __shared__ unsigned short Bs[64 * 32];
    int b = blockIdx.x, t = threadIdx.x;
    int l = t & 63, w = t >> 6, wi = w >> 1, wjq = w & 1, quad = l >> 4, lj = l & 15;
    f32x4 acc[2][2];
    if (b < 192) {
        int z = b >> 6, rem = b & 63;
        int j0 = (rem & 3) * 64, i0 = (rem >> 2) * 64;
        const unsigned short* A  = (z == 0) ? src_bf : tgt_bf;
        const unsigned short* Bt = (z == 0) ? WqT : (z == 1) ? WkT : WvT;
        const float* bias        = (z == 0) ? bq : (z == 1) ? bk : bv;
        mfma_tile64(A, Bt, HIDD, i0, j0, t, acc, As, Bs);
        #pragma unroll
        for (int rg = 0; rg < 2; ++rg)
            #pragma unroll
            for (int cg = 0; cg < 2; ++cg) {
                int col  = j0 + wjq * 32 + cg * 16 + lj;
                int row0 = i0 + wi * 32 + rg * 16 + quad * 4;
                float bb = bias[col];
                if (z < 2) {
                    unsigned short* obf = (z == 0) ? q_bf : k_bf;
                    #pragma unroll
                    for (int r = 0; r < 4; ++r)
                        obf[(row0 + r) * HIDD + col] = f2bf(acc[rg][cg][r] + bb);
                } else {
                    unsigned short vv[4];
                    #pragma unroll
                    for (int r = 0; r < 4; ++r) vv[r] = f2bf(acc[rg][cg][r] + bb);
                    *(int2*)&vT[col * NN + row0] = *(int2*)vv;
                }
            }
    } else {
        int b2 = b - 192;
        int j0 = (b2 & 15) * 64, i0 = (b2 >> 4) * 64;
        mfma_tile64(gateA, gaw1T, 512, i0, j0, t, acc, As, Bs);
        float p[8][2];
        #pragma unroll
        for (int s = 0; s < 8; ++s) { p[s][0] = 0.f; p[s][1] = 0.f; }
        #pragma unroll
        for (int cg = 0; cg < 2; ++cg) {
            int col = j0 + wjq * 32 + cg * 16 + lj;
            float w20 = gaw2[col * 2], w21 = gaw2[col * 2 + 1];
            float bb = gab1[col];
            #pragma unroll
            for (int rg = 0; rg < 2; ++rg)
                #pragma unroll
                for (int r = 0; r < 4; ++r) {
                    float hv = silu_f(acc[rg][cg][r] + bb);
                    p[rg * 4 + r][0] += hv * w20;
                    p[rg * 4 + r][1] += hv * w21;
                }
        }
        #pragma unroll
        for (int off = 1; off < 16; off <<= 1)
            #pragma unroll
            for (int s = 0; s < 8; ++s) {
                p[s][0] += __shfl_xor(p[s][0], off, 64);
                p[s][1] += __shfl_xor(p[s][1], off, 64);
            }
        if (lj == 0) {
            #pragma unroll
            for (int rg = 0; rg < 2; ++rg)
                #pragma unroll
                for (int r = 0; r < 4; ++r) {
                    int row = i0 + wi * 32 + rg * 16 + quad * 4 + r;
                    atomicAdd(&glog[row * 2],     p[rg * 4 + r][0]);
                    atomicAdd(&glog[row * 2 + 1], p[rg * 4 + r][1]);
                }
        }
    }
}

// ---------------- flash attention v2 ----------------
// grid (8 m-chunks of 128, 64 row-tiles of 16). 512 threads = 8 waves; wave w
// handles head h=w fully independently. Geo bias via 512-knot lerp table.

__global__ __launch_bounds__(512)
void flash_kernel(const unsigned short* __restrict__ qbf,
                  const unsigned short* __restrict__ kbf,
                  const unsigned short* __restrict__ vT,
                  const float* __restrict__ pos, const float* __restrict__ glog,
                  const float* __restrict__ gab2,
                  const unsigned* __restrict__ pbits, const float* __restrict__ t01,
                  const unsigned* __restrict__ gtab,
                  float* __restrict__ Opart, float* __restrict__ ml) {
    __shared__ unsigned geo2[4 * 16 * GS];      // 33.3 KB [h/2][i][j]
    __shared__ unsigned short Pb[8 * 16 * PSW]; // 34.8 KB, wave-private eighths
    __shared__ unsigned tabs[512 * 4];          // 8 KB geo lerp table
    __shared__ float posA[48], posB[384];
    __shared__ unsigned prowL[64];              // 16 rows x 4 words
    __shared__ float g01[32];
    __shared__ float t01s[16];
    int t  = threadIdx.x;
    int bx = blockIdx.x;               // m-chunk
    int n0 = blockIdx.y * 16;
    int mbase = bx * MC;
    *(uint4*)&tabs[t * 4] = *(const uint4*)&gtab[t * 4];
    if (t < 384) posB[t] = pos[mbase * 3 + t];
    if (t < 48)  posA[t] = pos[n0 * 3 + t];
    if (t < 64)  prowL[t] = pbits[(n0 + (t >> 2)) * NW + bx * 4 + (t & 3)];
    if (t < 16) {
        float L0 = glog[(n0 + t) * 2]     + gab2[0];
        float L1 = glog[(n0 + t) * 2 + 1] + gab2[1];
        float mx = fmaxf(L0, L1);
        float e0 = __expf(L0 - mx), e1 = __expf(L1 - mx);
        float inv = 1.0f / (e0 + e1);
        g01[2 * t]     = e0 * inv;
        g01[2 * t + 1] = e1 * inv;
    }
    if (t < 16) t01s[t] = t01[t];
    __syncthreads();

    // phase 1: dist + table lerp, 2048 pairs, 4 per thread
    for (int pp = 0; pp < 4; ++pp) {
        int p = pp * 512 + t;
        int i = p >> 7, j = p & (MC - 1);
        float dx = posA[i * 3]     - posB[j * 3];
        float dy = posA[i * 3 + 1] - posB[j * 3 + 1];
        float dz = posA[i * 3 + 2] - posB[j * 3 + 2];
        float dist = sqrtf(fmaxf(dx * dx + dy * dy + dz * dz, 1e-12f));
        float fx = fminf(dist * 32.0f, 510.999f);
        int ix = (int)fx;
        float fr = fx - (float)ix;
        const unsigned* tp = &tabs[ix * 4];
        #pragma unroll
        for (int h2 = 0; h2 < 4; ++h2) {
            unsigned ta = tp[h2], tb = tp[h2 + 4];
            float a0 = bf2f(ta & 0xffffu), a1 = bf2f(ta >> 16);
            float b0 = bf2f(tb & 0xffffu), b1 = bf2f(tb >> 16);
            geo2[h2 * 16 * GS + i * GS + j] =
                (unsigned)f2bf(a0 + (b0 - a0) * fr) |
                ((unsigned)f2bf(a1 + (b1 - a1) * fr) << 16);
        }
    }
    __syncthreads();

    int l = t & 63, w = t >> 6, quad = l >> 4, lj = l & 15;
    int h = w;                          // one head per wave
    unsigned short* Pw = &Pb[w * 16 * PSW];
    const float scale = 0.17677669529663687f;  // 1/sqrt(32)
    f32x4 z = {0.f, 0.f, 0.f, 0.f};

    // QK: 8 col-tiles of 16
    short8 a = *(const short8*)&qbf[(n0 + lj) * HIDD + h * 32 + quad * 8];
    f32x4 acc[8];
    #pragma unroll
    for (int tl = 0; tl < 8; ++tl) {
        short8 bfr = *(const short8*)&kbf[(mbase + tl * 16 + lj) * HIDD +
                                          h * 32 + quad * 8];
        acc[tl] = __builtin_amdgcn_mfma_f32_16x16x32_bf16(a, bfr, z, 0, 0, 0);
    }
    // bias add: row i=quad*4+r, col j=tl*16+lj (hoisted scalars, same math)
    float t0h = t01s[h], t1h = t01s[8 + h];
    float g0r[4], g1r[4];
    #pragma unroll
    for (int r = 0; r < 4; ++r) {
        g0r[r] = g01[2 * (quad * 4 + r)];
        g1r[r] = g01[2 * (quad * 4 + r) + 1];
    }
    #pragma unroll
    for (int tl = 0; tl < 8; ++tl) {
        int j = tl * 16 + lj;
        #pragma unroll
        for (int r = 0; r < 4; ++r) {
            int i = quad * 4 + r;
            unsigned gv = geo2[(h >> 1) * 16 * GS + i * GS + j];
            float geo_v = __uint_as_float((h & 1) ? (gv & 0xffff0000u) : (gv << 16));
            unsigned bit = (prowL[i * 4 + (j >> 5)] >> (j & 31)) & 1u;
            float tv = bit ? t1h : t0h;
            acc[tl][r] = acc[tl][r] * scale + g0r[r] * geo_v + g1r[r] * tv;
        }
    }
    // wave-internal row max (quads own disjoint rows; reduce over 16 lj)
    float mr[4];
    #pragma unroll
    for (int r = 0; r < 4; ++r) {
        float m01 = fmaxf(fmaxf(acc[0][r], acc[1][r]), fmaxf(acc[2][r], acc[3][r]));
        float m23 = fmaxf(fmaxf(acc[4][r], acc[5][r]), fmaxf(acc[6][r], acc[7][r]));
        mr[r] = fmaxf(m01, m23);
    }
    #pragma unroll
    for (int off = 1; off < 16; off <<= 1)
        #pragma unroll
        for (int r = 0; r < 4; ++r) mr[r] = fmaxf(mr[r], __shfl_xor(mr[r], off, 64));
    // exp, P -> wave-private LDS (A-layout), row sums
    float sm[4] = {0.f, 0.f, 0.f, 0.f};
    #pragma unroll
    for (int tl = 0; tl < 8; ++tl) {
        int j = tl * 16 + lj;
        #pragma unroll
        for (int r = 0; r < 4; ++r) {
            float e = __expf(acc[tl][r] - mr[r]);
            Pw[(quad * 4 + r) * PSW + j] = f2bf(e);
            sm[r] += e;
        }
    }
    #pragma unroll
    for (int off = 1; off < 16; off <<= 1)
        #pragma unroll
        for (int r = 0; r < 4; ++r) sm[r] += __shfl_xor(sm[r], off, 64);
    if (lj == 0) {
        #pragma unroll
        for (int r = 0; r < 4; ++r) {
            int i = quad * 4 + r;
            int base = ((bx * NN + n0 + i) * NH + h) * 2;
            ml[base] = mr[r]; ml[base + 1] = sm[r];
        }
    }
    // PV: K=128, 2 d-tiles; same-wave DS ordering makes this safe w/o barrier
    f32x4 o[2] = {z, z};
    #pragma unroll
    for (int ks = 0; ks < 4; ++ks) {
        short8 aP = *(short8*)&Pw[lj * PSW + ks * 32 + quad * 8];
        #pragma unroll
        for (int dt = 0; dt < 2; ++dt) {
            short8 bV = *(const short8*)&vT[(h * 32 + dt * 16 + lj) * NN +
                                            mbase + ks * 32 + quad * 8];
            o[dt] = __builtin_amdgcn_mfma_f32_16x16x32_bf16(aP, bV, o[dt], 0, 0, 0);
        }
    }
    #pragma unroll
    for (int dt = 0; dt < 2; ++dt)
        #pragma unroll
        for (int r = 0; r < 4; ++r)
            Opart[((long)(bx * NN + n0 + quad * 4 + r)) * HIDD +
                  h * 32 + dt * 16 + lj] = o[dt][r];
}

// ---------------- combine + Wo projection + residual + LayerNorm ----------------
// 512 threads: combine (16r x 32c slices), GEMM over 8 waves, LN 2 rows/wave.

#define PS 264

__global__ __launch_bounds__(512)
void wo_ln_kernel(const float* __restrict__ Opart, const float* __restrict__ ml,
                  const unsigned short* __restrict__ WoT,
                  const float* __restrict__ bo, const float* __restrict__ xres,
                  const float* __restrict__ lng, const float* __restrict__ lnb,
                  float* __restrict__ out) {
    __shared__ unsigned short Asm[16 * PS];
    __shared__ float Osm[16][260];
    __shared__ float Lg[256], Lb[256];
    __shared__ float wc[16][NH][NCH];
    __shared__ float invl[16][NH];
    int t = threadIdx.x;
    int r0 = blockIdx.x * 16;
    if (t < 256) { Lg[t] = lng[t]; Lb[t] = lnb[t]; }
    if (t < 128) {
        int r = t >> 3, h = t & 7;
        float mm[NCH], ll[NCH];
        float M = -1e30f;
        #pragma unroll
        for (int ch = 0; ch < NCH; ++ch) {
            int base = ((ch * NN + r0 + r) * NH + h) * 2;
            mm[ch] = ml[base]; ll[ch] = ml[base + 1];
            M = fmaxf(M, mm[ch]);
        }
        float lt = 0.f;
        #pragma unroll
        for (int ch = 0; ch < NCH; ++ch) {
            float wv = __expf(mm[ch] - M);
            wc[r][h][ch] = wv;
            lt += wv * ll[ch];
        }
        invl[r][h] = 1.0f / lt;
    }
    __syncthreads();
    {
        int r = t >> 5, c0 = t & 31;    // 16 rows x 32 cols per pass, 8 passes
        #pragma unroll
        for (int cc = 0; cc < 8; ++cc) {
            int c = cc * 32 + c0;
            int h = c >> 5;             // == cc
            float v = 0.f;
            #pragma unroll
            for (int ch = 0; ch < NCH; ++ch)
                v += wc[r][h][ch] * Opart[((long)(ch * NN + r0 + r)) * HIDD + c];
            Asm[r * PS + c] = f2bf(v * invl[r][h]);
        }
    }
    __syncthreads();
    int l = t & 63, w = t >> 6, quad = l >> 4, lj = l & 15;
    f32x4 z = {0.f, 0.f, 0.f, 0.f};
    f32x4 acc[2] = {z, z};
    for (int ks = 0; ks < 8; ++ks) {
        short8 a = *(short8*)&Asm[lj * PS + ks * 32 + quad * 8];
        #pragma unroll
        for (int nt = 0; nt < 2; ++nt) {
            int col = w * 32 + nt * 16 + lj;
            short8 bfr = *(const short8*)&WoT[col * HIDD + ks * 32 + quad * 8];
            acc[nt] = __builtin_amdgcn_mfma_f32_16x16x32_bf16(a, bfr, acc[nt], 0, 0, 0);
        }
    }
    #pragma unroll
    for (int nt = 0; nt < 2; ++nt) {
        int col = w * 32 + nt * 16 + lj;
        float bb = bo[col];
        #pragma unroll
        for (int r = 0; r < 4; ++r)
            Osm[quad * 4 + r][col] = acc[nt][r] + bb;
    }
    __syncthreads();
    #pragma unroll
    for (int rr = 0; rr < 2; ++rr) {
        int row = w * 2 + rr;
        float4 o  = *(float4*)&Osm[row][l * 4];
        float4 s4 = *(const float4*)&xres[(r0 + row) * HIDD + l * 4];
        float x0 = o.x + s4.x, x1 = o.y + s4.y, x2 = o.z + s4.z, x3 = o.w + s4.w;
        float sum = x0 + x1 + x2 + x3;
        float ss  = x0 * x0 + x1 * x1 + x2 * x2 + x3 * x3;
        #pragma unroll
        for (int off = 32; off > 0; off >>= 1) {
            sum += __shfl_xor(sum, off, 64);
            ss  += __shfl_xor(ss,  off, 64);
        }
        float mean = sum * (1.0f / HIDD);
        float var  = ss * (1.0f / HIDD) - mean * mean;
        float rstd = rsqrtf(var + 1e-5f);
        float4 ov;
        ov.x = (x0 - mean) * rstd * Lg[l * 4]     + Lb[l * 4];
        ov.y = (x1 - mean) * rstd * Lg[l * 4 + 1] + Lb[l * 4 + 1];
        ov.z = (x2 - mean) * rstd * Lg[l * 4 + 2] + Lb[l * 4 + 2];
        ov.w = (x3 - mean) * rstd * Lg[l * 4 + 3] + Lb[l * 4 + 3];
        *(float4*)&out[(r0 + row) * HIDD + l * 4] = ov;
    }
}

// ---------------- host ----------------

extern "C" void kernel_launch(void* const* d_in, const int* in_sizes, int n_in,
                              void* d_out, int out_size, void* d_ws, size_t ws_size,
                              hipStream_t stream) {
    const float* src  = (const float*)d_in[0];
    const float* tgt  = (const float*)d_in[1];
    const float* pos  = (const float*)d_in[2];
    const int*   ei   = (const int*)d_in[3];
    const float* Wq   = (const float*)d_in[4];  const float* bq  = (const float*)d_in[5];
    const float* Wk   = (const float*)d_in[6];  const float* bk  = (const float*)d_in[7];
    const float* Wv   = (const float*)d_in[8];  const float* bv  = (const float*)d_in[9];
    const float* gw1  = (const float*)d_in[10]; const float* gb1 = (const float*)d_in[11];
    const float* gw2  = (const float*)d_in[12]; const float* gb2 = (const float*)d_in[13];
    const float* tw1  = (const float*)d_in[14]; const float* tb1 = (const float*)d_in[15];
    const float* tw2  = (const float*)d_in[16]; const float* tb2 = (const float*)d_in[17];
    const float* gaw1 = (const float*)d_in[18]; const float* gab1= (const float*)d_in[19];
    const float* gaw2 = (const float*)d_in[20]; const float* gab2= (const float*)d_in[21];
    const float* Wo   = (const float*)d_in[22]; const float* bo  = (const float*)d_in[23];
    const float* lng  = (const float*)d_in[24]; const float* lnb = (const float*)d_in[25];
    int E = in_sizes[3] / 2;

    char* w = (char*)d_ws;
    unsigned* p0   = (unsigned*)w; w += NN * NW * 4;        // zeroed (adj rows)
    float* glog    = (float*)w;    w += NN * 2 * 4;         // zeroed (contiguous)
    unsigned* bar  = (unsigned*)w; w += 64;                 // zeroed (grid barrier)
    unsigned* p1   = (unsigned*)w; w += NN * NW * 4;
    unsigned* p2   = (unsigned*)w; w += NN * NW * 4;
    unsigned short* src_bf = (unsigned short*)w; w += NN * HIDD * 2;
    unsigned short* tgt_bf = (unsigned short*)w; w += NN * HIDD * 2;
    unsigned short* gateA  = (unsigned short*)w; w += NN * 512 * 2;
    unsigned short* WqT    = (unsigned short*)w; w += HIDD * HIDD * 2;
    unsigned short* WkT    = (unsigned short*)w; w += HIDD * HIDD * 2;
    unsigned short* WvT    = (unsigned short*)w; w += HIDD * HIDD * 2;
    unsigned short* WoT    = (unsigned short*)w; w += HIDD * HIDD * 2;
    unsigned short* gaw1T  = (unsigned short*)w; w += 1024 * 512 * 2;
    unsigned short* q_bf   = (unsigned short*)w; w += NN * HIDD * 2;
    unsigned short* k_bf   = (unsigned short*)w; w += NN * HIDD * 2;
    unsigned short* vT     = (unsigned short*)w; w += HIDD * NN * 2;   // [256][1024]
    float* t01  = (float*)w; w += 256;
    unsigned* gtab = (unsigned*)w; w += 512 * 16;               // 8 KB geo table
    float* Opart = (float*)w; w += (long)NCH * NN * HIDD * 4;   // 8 MB
    float* mlb   = (float*)w; w += (long)NCH * NN * NH * 2 * 4; // 512 KB

    int nsc = (E + 255) / 256;

    // zero p0 (adj rows) + glog + barrier counter (contiguous)
    hipMemsetAsync(p0, 0, NN * NW * 4 + NN * 2 * 4 + 64, stream);

    prep_kernel<<<1027 + nsc, 256, 0, stream>>>(src, tgt, Wq, Wk, Wv, Wo, gaw1,
                                                tw1, tb1, tw2, tb2,
                                                gw1, gb1, gw2, gb2, ei, E,
                                                src_bf, tgt_bf, gateA,
                                                WqT, WkT, WvT, WoT, gaw1T,
                                                t01, gtab, p0);

    // all 3 path iterations in one kernel (grid barrier); final path in p1
    path3_kernel<<<256, 256, 0, stream>>>(p0, p1, p2, bar);

    proj_kernel<<<448, 256, 0, stream>>>(src_bf, tgt_bf, gateA, WqT, WkT, WvT, gaw1T,
                                         bq, bk, bv, gab1, gaw2,
                                         q_bf, k_bf, vT, glog);

    flash_kernel<<<dim3(NCH, 64), 512, 0, stream>>>(q_bf, k_bf, vT, pos, glog, gab2,
                                                    p1, t01, gtab, Opart, mlb);

    wo_ln_kernel<<<NN / 16, 512, 0, stream>>>(Opart, mlb, WoT, bo, src, lng, lnb,
                                              (float*)d_out);
}

// Round 4
// 179.141 us; speedup vs baseline: 1.5892x; 1.5892x over previous
//
#include <hip/hip_runtime.h>
#include <math.h>

#define NN   1024
#define HIDD 256
#define NH   8
#define NW   32   // 1024 bits / 32 per word
#define MC   128  // flash m-chunk size
#define NCH  8    // flash chunks
#define GS   130  // geo2 row stride (dwords) — quad banks 0/8/16/24, 2-way free
#define PSW  136  // Pb row stride (shorts)

typedef __attribute__((ext_vector_type(8))) short short8;
typedef __attribute__((ext_vector_type(4))) float f32x4;

__device__ __forceinline__ float silu_f(float x) {
    // x * sigmoid(x); v_rcp instead of full-precision div chain (~1ulp rel err)
    return x * __builtin_amdgcn_rcpf(1.0f + __expf(-x));
}
__device__ __forceinline__ unsigned short f2bf(float x) {
    unsigned b = __float_as_uint(x);
    return (unsigned short)((b + 0x7FFFu + ((b >> 16) & 1u)) >> 16);
}
__device__ __forceinline__ float bf2f(unsigned u) {
    return __uint_as_float(u << 16);
}

// ---------------- fused prep ----------------
// b <  256 : feature f32->bf16 conversion, 8 elems/thread, vectorized
// b < 1024 : weight transposes (QKVO 256, gate W1 512)
// b == 1024: topo 2-entry table (path bit 0/1)
// b == 1025/1026: geo MLP table — 512 knots over dist in [0,16], bf16 packed
// b >= 1027: edge scatter -> row bitsets

__global__ __launch_bounds__(256)
void prep_kernel(const float* __restrict__ src, const float* __restrict__ tgt,
                 const float* __restrict__ Wq, const float* __restrict__ Wk,
                 const float* __restrict__ Wv, const float* __restrict__ Wo,
                 const float* __restrict__ gaw1,
                 const float* __restrict__ tw1, const float* __restrict__ tb1,
                 const float* __restrict__ tw2, const float* __restrict__ tb2,
                 const float* __restrict__ gw1, const float* __restrict__ gb1,
                 const float* __restrict__ gw2, const float* __restrict__ gb2,
                 const int* __restrict__ ei, int E,
                 unsigned short* __restrict__ src_bf, unsigned short* __restrict__ tgt_bf,
                 unsigned short* __restrict__ gateA,
                 unsigned short* __restrict__ WqT, unsigned short* __restrict__ WkT,
                 unsigned short* __restrict__ WvT, unsigned short* __restrict__ WoT,
                 unsigned short* __restrict__ gaw1T,
                 float* __restrict__ t01, unsigned* __restrict__ gtab,
                 unsigned* __restrict__ prow) {
    __shared__ float tile[32][33];
    int b = blockIdx.x, t = threadIdx.x;
    if (b < 256) {
        int idx = b * 256 + t;          // 65536 threads, 8 elems each
        int n = idx >> 6, g = idx & 63;
        int j = g * 8;
        const float* base = (g < 32) ? (src + n * 256 + j)
                                     : (tgt + n * 256 + j - 256);
        float4 v0 = *(const float4*)base;
        float4 v1 = *(const float4*)(base + 4);
        unsigned short u[8] = {f2bf(v0.x), f2bf(v0.y), f2bf(v0.z), f2bf(v0.w),
                               f2bf(v1.x), f2bf(v1.y), f2bf(v1.z), f2bf(v1.w)};
        int4 pk = *(int4*)u;
        *(int4*)&gateA[n * 512 + j] = pk;
        if (g < 32) *(int4*)&src_bf[n * 256 + j] = pk;
        else        *(int4*)&tgt_bf[n * 256 + j - 256] = pk;
    } else if (b < 1024) {
        int b2 = b - 256;
        const float* W; unsigned short* Wt; int Kd, Nd, n0, k0;
        if (b2 < 256) {
            int which = b2 >> 6, tl = b2 & 63;
            W  = (which == 0) ? Wq : (which == 1) ? Wk : (which == 2) ? Wv : Wo;
            Wt = (which == 0) ? WqT : (which == 1) ? WkT : (which == 2) ? WvT : WoT;
            Kd = 256; Nd = 256;
            n0 = (tl & 7) * 32; k0 = (tl >> 3) * 32;
        } else {
            int b3 = b2 - 256;
            W = gaw1; Wt = gaw1T; Kd = 512; Nd = 1024;
            n0 = (b3 & 31) * 32; k0 = (b3 >> 5) * 32;
        }
        int tx = t & 31, ty = t >> 5;
        #pragma unroll
        for (int p = 0; p < 4; ++p)
            tile[ty + p * 8][tx] = W[(k0 + ty + p * 8) * (long)Nd + n0 + tx];
        __syncthreads();
        #pragma unroll
        for (int p = 0; p < 4; ++p)
            Wt[(n0 + ty + p * 8) * (long)Kd + k0 + tx] = f2bf(tile[tx][ty + p * 8]);
    } else if (b == 1024) {
        if (t < 16) {
            int h = t & 7;
            float x = (t >> 3) ? 1.0f : 0.0f;
            float acc = tb2[h];
            for (int c = 0; c < 32; ++c)
                acc += silu_f(x * tw1[c] + tb1[c]) * tw2[c * 8 + h];
            t01[t] = acc;
        }
    } else if (b == 1025 || b == 1026) {
        int e = (b - 1025) * 256 + t;   // knot 0..511, dist = e/32
        float d = (float)e * 0.03125f;
        float go[8];
        #pragma unroll
        for (int h = 0; h < 8; ++h) go[h] = gb2[h];
        for (int c = 0; c < 32; ++c) {
            float hh = silu_f(d * gw1[c] + gb1[c]);
            #pragma unroll
            for (int h = 0; h < 8; ++h) go[h] += hh * gw2[c * 8 + h];
        }
        #pragma unroll
        for (int h2 = 0; h2 < 4; ++h2)
            gtab[e * 4 + h2] = (unsigned)f2bf(go[2 * h2]) |
                               ((unsigned)f2bf(go[2 * h2 + 1]) << 16);
    } else {
        int e = (b - 1027) * 256 + t;
        if (e < E) {
            int r = ei[e], c = ei[E + e];
            if ((unsigned)r < NN && (unsigned)c < NN)
                atomicOr(&prow[r * NW + (c >> 5)], 1u << (c & 31));
        }
    }
}

// ---------------- path propagation: 3 iters, row-local, ZERO barriers -------
// path = min(path, path @ adj) with adj STATIC:
//   out_row_i = row_i AND (OR over set bits k of row_i of adj_row_k).
// Each iteration depends only on this wave's OWN current row (registers) and
// static adj rows -> the whole 3-iteration chain is row-local. No grid sync,
// no multi-launch. Rows only sparsify (row ⊆ adj_row), so bit-walks stay short.

__global__ __launch_bounds__(256)
void path3_kernel(const unsigned* __restrict__ arow,   // adjacency (static)
                  unsigned* __restrict__ pout) {
    int t  = threadIdx.x;
    int l  = t & 63;
    int wj = l & 31;
    int i  = blockIdx.x * 4 + (t >> 6);
    unsigned r = arow[i * NW + wj];     // lane wj holds word wj of row i
    #pragma unroll
    for (int it = 0; it < 3; ++it) {
        unsigned acc = 0u;
        for (int w2 = 0; w2 < NW; ++w2) {
            unsigned m = __shfl(r, w2, 64);   // wave-uniform word w2 of own row
            while (m) {
                int bb = __ffs(m) - 1;
                m &= m - 1;
                acc |= arow[(((w2 << 5) | bb)) * NW + wj];
            }
        }
        r &= acc;
    }
    if (l < 32) pout[i * NW + wj] = r;
}

// ---------------- shared MFMA 64x64 tile (register-prefetch pipeline) -------

__device__ __forceinline__ void mfma_tile64(const unsigned short* __restrict__ A,
                                            const unsigned short* __restrict__ Bt,
                                            int K, int i0, int j0, int t,
                                            f32x4 acc[2][2],
                                            unsigned short* As, unsigned short* Bs) {
    int l = t & 63, w = t >> 6;
    int wi = w >> 1, wj = w & 1;
    int quad = l >> 4, lj = l & 15;
    int sr = t >> 2, skp = (t & 3) * 8;
    f32x4 z = {0.f, 0.f, 0.f, 0.f};
    acc[0][0] = z; acc[0][1] = z; acc[1][0] = z; acc[1][1] = z;
    const unsigned short* pa = &A[(i0 + sr) * (long)K + skp];
    const unsigned short* pb = &Bt[(j0 + sr) * (long)K + skp];
    int4 ra = *(const int4*)pa;
    int4 rb = *(const int4*)pb;
    for (int k0 = 0; k0 < K; k0 += 32) {
        *(int4*)&As[sr * 32 + skp] = ra;
        *(int4*)&Bs[sr * 32 + skp] = rb;
        __syncthreads();
        if (k0 + 32 < K) {              // prefetch next tile; hides under MFMAs
            ra = *(const int4*)(pa + k0 + 32);
            rb = *(const int4*)(pb + k0 + 32);
        }
        short8 a0 = *(short8*)&As[(wi * 32 + lj) * 32 + quad * 8];
        short8 a1 = *(short8*)&As[(wi * 32 + 16 + lj) * 32 + quad * 8];
        short8 b0 = *(short8*)&Bs[(wj * 32 + lj) * 32 + quad * 8];
        short8 b1 = *(short8*)&Bs[(wj * 32 + 16 + lj) * 32 + quad * 8];
        acc[0][0] = __builtin_amdgcn_mfma_f32_16x16x32_bf16(a0, b0, acc[0][0], 0, 0, 0);
        acc[0][1] = __builtin_amdgcn_mfma_f32_16x16x32_bf16(a0, b1, acc[0][1], 0, 0, 0);
        acc[1][0] = __builtin_amdgcn_mfma_f32_16x16x32_bf16(a1, b0, acc[1][0], 0, 0, 0);
        acc[1][1] = __builtin_amdgcn_mfma_f32_16x16x32_bf16(a1, b1, acc[1][1], 0, 0, 0);
        __syncthreads();
    }
}

// ---------------- projections: QKV (192) + gate hidden w/ fused logits (256) --

__global__ __launch_bounds__(256)
void proj_kernel(const unsigned short* __restrict__ src_bf,
                 const unsigned short* __restrict__ tgt_bf,
                 const unsigned short* __restrict__ gateA,
                 const unsigned short* __restrict__ WqT,
                 const unsigned short* __restrict__ WkT,
                 const unsigned short* __restrict__ WvT,
                 const unsigned short* __restrict__ gaw1T,
                 const float* __restrict__ bq, const float* __restrict__ bk,
                 const float* __restrict__ bv, const float* __restrict__ gab1,
                 const float* __restrict__ gaw2,
                 unsigned short* __restrict__ q_bf, unsigned short* __restrict__ k_bf,
                 unsigned short* __restrict__ vT, float* __restrict__ glog) {
    __shared__ unsigned short As[64 * 32];
    __shared__ unsigned short Bs[64 * 32];
    int b = blockIdx.x, t = threadIdx.x;
    int l = t & 63, w = t >> 6, wi = w >> 1, wjq = w & 1, quad = l >> 4, lj = l & 15;
    f32x4 acc[2][2];
    if (b < 192) {
        int z = b >> 6, rem = b & 63;
        int j0 = (rem & 3) * 64, i0 = (rem >> 2) * 64;
        const unsigned short* A  = (z == 0) ? src_bf : tgt_bf;
        const unsigned short* Bt = (z == 0) ? WqT : (z == 1) ? WkT : WvT;
        const float* bias        = (z == 0) ? bq : (z == 1) ? bk : bv;
        mfma_tile64(A, Bt, HIDD, i0, j0, t, acc, As, Bs);
        #pragma unroll
        for (int rg = 0; rg < 2; ++rg)
            #pragma unroll
            for (int cg = 0; cg < 2; ++cg) {
                int col  = j0 + wjq * 32 + cg * 16 + lj;
                int row0 = i0 + wi * 32 + rg * 16 + quad * 4;
                float bb = bias[col];
                if (z < 2) {
                    unsigned short* obf = (z == 0) ? q_bf : k_bf;
                    #pragma unroll
                    for (int r = 0; r < 4; ++r)
                        obf[(row0 + r) * HIDD + col] = f2bf(acc[rg][cg][r] + bb);
                } else {
                    unsigned short vv[4];
                    #pragma unroll
                    for (int r = 0; r < 4; ++r) vv[r] = f2bf(acc[rg][cg][r] + bb);
                    *(int2*)&vT[col * NN + row0] = *(int2*)vv;
                }
            }
    } else {
        int b2 = b - 192;
        int j0 = (b2 & 15) * 64, i0 = (b2 >> 4) * 64;
        mfma_tile64(gateA, gaw1T, 512, i0, j0, t, acc, As, Bs);
        float p[8][2];
        #pragma unroll
        for (int s = 0; s < 8; ++s) { p[s][0] = 0.f; p[s][1] = 0.f; }
        #pragma unroll
        for (int cg = 0; cg < 2; ++cg) {
            int col = j0 + wjq * 32 + cg * 16 + lj;
            float w20 = gaw2[col * 2], w21 = gaw2[col * 2 + 1];
            float bb = gab1[col];
            #pragma unroll
            for (int rg = 0; rg < 2; ++rg)
                #pragma unroll
                for (int r = 0; r < 4; ++r) {
                    float hv = silu_f(acc[rg][cg][r] + bb);
                    p[rg * 4 + r][0] += hv * w20;
                    p[rg * 4 + r][1] += hv * w21;
                }
        }
        #pragma unroll
        for (int off = 1; off < 16; off <<= 1)
            #pragma unroll
            for (int s = 0; s < 8; ++s) {
                p[s][0] += __shfl_xor(p[s][0], off, 64);
                p[s][1] += __shfl_xor(p[s][1], off, 64);
            }
        if (lj == 0) {
            #pragma unroll
            for (int rg = 0; rg < 2; ++rg)
                #pragma unroll
                for (int r = 0; r < 4; ++r) {
                    int row = i0 + wi * 32 + rg * 16 + quad * 4 + r;
                    atomicAdd(&glog[row * 2],     p[rg * 4 + r][0]);
                    atomicAdd(&glog[row * 2 + 1], p[rg * 4 + r][1]);
                }
        }
    }
}

// ---------------- flash attention v2 ----------------
// grid (8 m-chunks of 128, 64 row-tiles of 16). 512 threads = 8 waves; wave w
// handles head h=w fully independently. Geo bias via 512-knot lerp table.

__global__ __launch_bounds__(512)
void flash_kernel(const unsigned short* __restrict__ qbf,
                  const unsigned short* __restrict__ kbf,
                  const unsigned short* __restrict__ vT,
                  const float* __restrict__ pos, const float* __restrict__ glog,
                  const float* __restrict__ gab2,
                  const unsigned* __restrict__ pbits, const float* __restrict__ t01,
                  const unsigned* __restrict__ gtab,
                  float* __restrict__ Opart, float* __restrict__ ml) {
    __shared__ unsigned geo2[4 * 16 * GS];      // 33.3 KB [h/2][i][j]
    __shared__ unsigned short Pb[8 * 16 * PSW]; // 34.8 KB, wave-private eighths
    __shared__ unsigned tabs[512 * 4];          // 8 KB geo lerp table
    __shared__ float posA[48], posB[384];
    __shared__ unsigned prowL[64];              // 16 rows x 4 words
    __shared__ float g01[32];
    __shared__ float t01s[16];
    int t  = threadIdx.x;
    int bx = blockIdx.x;               // m-chunk
    int n0 = blockIdx.y * 16;
    int mbase = bx * MC;
    *(uint4*)&tabs[t * 4] = *(const uint4*)&gtab[t * 4];
    if (t < 384) posB[t] = pos[mbase * 3 + t];
    if (t < 48)  posA[t] = pos[n0 * 3 + t];
    if (t < 64)  prowL[t] = pbits[(n0 + (t >> 2)) * NW + bx * 4 + (t & 3)];
    if (t < 16) {
        float L0 = glog[(n0 + t) * 2]     + gab2[0];
        float L1 = glog[(n0 + t) * 2 + 1] + gab2[1];
        float mx = fmaxf(L0, L1);
        float e0 = __expf(L0 - mx), e1 = __expf(L1 - mx);
        float inv = 1.0f / (e0 + e1);
        g01[2 * t]     = e0 * inv;
        g01[2 * t + 1] = e1 * inv;
    }
    if (t < 16) t01s[t] = t01[t];
    __syncthreads();

    // phase 1: dist + table lerp, 2048 pairs, 4 per thread
    for (int pp = 0; pp < 4; ++pp) {
        int p = pp * 512 + t;
        int i = p >> 7, j = p & (MC - 1);
        float dx = posA[i * 3]     - posB[j * 3];
        float dy = posA[i * 3 + 1] - posB[j * 3 + 1];
        float dz = posA[i * 3 + 2] - posB[j * 3 + 2];
        float dist = sqrtf(fmaxf(dx * dx + dy * dy + dz * dz, 1e-12f));
        float fx = fminf(dist * 32.0f, 510.999f);
        int ix = (int)fx;
        float fr = fx - (float)ix;
        const unsigned* tp = &tabs[ix * 4];
        #pragma unroll
        for (int h2 = 0; h2 < 4; ++h2) {
            unsigned ta = tp[h2], tb = tp[h2 + 4];
            float a0 = bf2f(ta & 0xffffu), a1 = bf2f(ta >> 16);
            float b0 = bf2f(tb & 0xffffu), b1 = bf2f(tb >> 16);
            geo2[h2 * 16 * GS + i * GS + j] =
                (unsigned)f2bf(a0 + (b0 - a0) * fr) |
                ((unsigned)f2bf(a1 + (b1 - a1) * fr) << 16);
        }
    }
    __syncthreads();

    int l = t & 63, w = t >> 6, quad = l >> 4, lj = l & 15;
    int h = w;                          // one head per wave
    unsigned short* Pw = &Pb[w * 16 * PSW];
    const float scale = 0.17677669529663687f;  // 1/sqrt(32)
    f32x4 z = {0.f, 0.f, 0.f, 0.f};

    // QK: 8 col-tiles of 16
    short8 a = *(const short8*)&qbf[(n0 + lj) * HIDD + h * 32 + quad * 8];
    f32x4 acc[8];
    #pragma unroll
    for (int tl = 0; tl < 8; ++tl) {
        short8 bfr = *(const short8*)&kbf[(mbase + tl * 16 + lj) * HIDD +
                                          h * 32 + quad * 8];
        acc[tl] = __builtin_amdgcn_mfma_f32_16x16x32_bf16(a, bfr, z, 0, 0, 0);
    }
    // bias add: row i=quad*4+r, col j=tl*16+lj (hoisted scalars, same math)
    float t0h = t01s[h], t1h = t01s[8 + h];
    float g0r[4], g1r[4];
    #pragma unroll
    for (int r = 0; r < 4; ++r) {
        g0r[r] = g01[2 * (quad * 4 + r)];
        g1r[r] = g01[2 * (quad * 4 + r) + 1];
    }
    #pragma unroll
    for (int tl = 0; tl < 8; ++tl) {
        int j = tl * 16 + lj;
        #pragma unroll
        for (int r = 0; r < 4; ++r) {
            int i = quad * 4 + r;
            unsigned gv = geo2[(h >> 1) * 16 * GS + i * GS + j];
            float geo_v = __uint_as_float((h & 1) ? (gv & 0xffff0000u) : (gv << 16));
            unsigned bit = (prowL[i * 4 + (j >> 5)] >> (j & 31)) & 1u;
            float tv = bit ? t1h : t0h;
            acc[tl][r] = acc[tl][r] * scale + g0r[r] * geo_v + g1r[r] * tv;
        }
    }
    // wave-internal row max (quads own disjoint rows; reduce over 16 lj)
    float mr[4];
    #pragma unroll
    for (int r = 0; r < 4; ++r) {
        float m01 = fmaxf(fmaxf(acc[0][r], acc[1][r]), fmaxf(acc[2][r], acc[3][r]));
        float m23 = fmaxf(fmaxf(acc[4][r], acc[5][r]), fmaxf(acc[6][r], acc[7][r]));
        mr[r] = fmaxf(m01, m23);
    }
    #pragma unroll
    for (int off = 1; off < 16; off <<= 1)
        #pragma unroll
        for (int r = 0; r < 4; ++r) mr[r] = fmaxf(mr[r], __shfl_xor(mr[r], off, 64));
    // exp, P -> wave-private LDS (A-layout), row sums
    float sm[4] = {0.f, 0.f, 0.f, 0.f};
    #pragma unroll
    for (int tl = 0; tl < 8; ++tl) {
        int j = tl * 16 + lj;
        #pragma unroll
        for (int r = 0; r < 4; ++r) {
            float e = __expf(acc[tl][r] - mr[r]);
            Pw[(quad * 4 + r) * PSW + j] = f2bf(e);
            sm[r] += e;
        }
    }
    #pragma unroll
    for (int off = 1; off < 16; off <<= 1)
        #pragma unroll
        for (int r = 0; r < 4; ++r) sm[r] += __shfl_xor(sm[r], off, 64);
    if (lj == 0) {
        #pragma unroll
        for (int r = 0; r < 4; ++r) {
            int i = quad * 4 + r;
            int base = ((bx * NN + n0 + i) * NH + h) * 2;
            ml[base] = mr[r]; ml[base + 1] = sm[r];
        }
    }
    // PV: K=128, 2 d-tiles; same-wave DS ordering makes this safe w/o barrier
    f32x4 o[2] = {z, z};
    #pragma unroll
    for (int ks = 0; ks < 4; ++ks) {
        short8 aP = *(short8*)&Pw[lj * PSW + ks * 32 + quad * 8];
        #pragma unroll
        for (int dt = 0; dt < 2; ++dt) {
            short8 bV = *(const short8*)&vT[(h * 32 + dt * 16 + lj) * NN +
                                            mbase + ks * 32 + quad * 8];
            o[dt] = __builtin_amdgcn_mfma_f32_16x16x32_bf16(aP, bV, o[dt], 0, 0, 0);
        }
    }
    #pragma unroll
    for (int dt = 0; dt < 2; ++dt)
        #pragma unroll
        for (int r = 0; r < 4; ++r)
            Opart[((long)(bx * NN + n0 + quad * 4 + r)) * HIDD +
                  h * 32 + dt * 16 + lj] = o[dt][r];
}

// ---------------- combine + Wo projection + residual + LayerNorm ----------------
// 512 threads: combine (16r x 32c slices), GEMM over 8 waves, LN 2 rows/wave.

#define PS 264

__global__ __launch_bounds__(512)
void wo_ln_kernel(const float* __restrict__ Opart, const float* __restrict__ ml,
                  const unsigned short* __restrict__ WoT,
                  const float* __restrict__ bo, const float* __restrict__ xres,
                  const float* __restrict__ lng, const float* __restrict__ lnb,
                  float* __restrict__ out) {
    __shared__ unsigned short Asm[16 * PS];
    __shared__ float Osm[16][260];
    __shared__ float Lg[256], Lb[256];
    __shared__ float wc[16][NH][NCH];
    __shared__ float invl[16][NH];
    int t = threadIdx.x;
    int r0 = blockIdx.x * 16;
    if (t < 256) { Lg[t] = lng[t]; Lb[t] = lnb[t]; }
    if (t < 128) {
        int r = t >> 3, h = t & 7;
        float mm[NCH], ll[NCH];
        float M = -1e30f;
        #pragma unroll
        for (int ch = 0; ch < NCH; ++ch) {
            int base = ((ch * NN + r0 + r) * NH + h) * 2;
            mm[ch] = ml[base]; ll[ch] = ml[base + 1];
            M = fmaxf(M, mm[ch]);
        }
        float lt = 0.f;
        #pragma unroll
        for (int ch = 0; ch < NCH; ++ch) {
            float wv = __expf(mm[ch] - M);
            wc[r][h][ch] = wv;
            lt += wv * ll[ch];
        }
        invl[r][h] = 1.0f / lt;
    }
    __syncthreads();
    {
        int r = t >> 5, c0 = t & 31;    // 16 rows x 32 cols per pass, 8 passes
        #pragma unroll
        for (int cc = 0; cc < 8; ++cc) {
            int c = cc * 32 + c0;
            int h = c >> 5;             // == cc
            float v = 0.f;
            #pragma unroll
            for (int ch = 0; ch < NCH; ++ch)
                v += wc[r][h][ch] * Opart[((long)(ch * NN + r0 + r)) * HIDD + c];
            Asm[r * PS + c] = f2bf(v * invl[r][h]);
        }
    }
    __syncthreads();
    int l = t & 63, w = t >> 6, quad = l >> 4, lj = l & 15;
    f32x4 z = {0.f, 0.f, 0.f, 0.f};
    f32x4 acc[2] = {z, z};
    for (int ks = 0; ks < 8; ++ks) {
        short8 a = *(short8*)&Asm[lj * PS + ks * 32 + quad * 8];
        #pragma unroll
        for (int nt = 0; nt < 2; ++nt) {
            int col = w * 32 + nt * 16 + lj;
            short8 bfr = *(const short8*)&WoT[col * HIDD + ks * 32 + quad * 8];
            acc[nt] = __builtin_amdgcn_mfma_f32_16x16x32_bf16(a, bfr, acc[nt], 0, 0, 0);
        }
    }
    #pragma unroll
    for (int nt = 0; nt < 2; ++nt) {
        int col = w * 32 + nt * 16 + lj;
        float bb = bo[col];
        #pragma unroll
        for (int r = 0; r < 4; ++r)
            Osm[quad * 4 + r][col] = acc[nt][r] + bb;
    }
    __syncthreads();
    #pragma unroll
    for (int rr = 0; rr < 2; ++rr) {
        int row = w * 2 + rr;
        float4 o  = *(float4*)&Osm[row][l * 4];
        float4 s4 = *(const float4*)&xres[(r0 + row) * HIDD + l * 4];
        float x0 = o.x + s4.x, x1 = o.y + s4.y, x2 = o.z + s4.z, x3 = o.w + s4.w;
        float sum = x0 + x1 + x2 + x3;
        float ss  = x0 * x0 + x1 * x1 + x2 * x2 + x3 * x3;
        #pragma unroll
        for (int off = 32; off > 0; off >>= 1) {
            sum += __shfl_xor(sum, off, 64);
            ss  += __shfl_xor(ss,  off, 64);
        }
        float mean = sum * (1.0f / HIDD);
        float var  = ss * (1.0f / HIDD) - mean * mean;
        float rstd = rsqrtf(var + 1e-5f);
        float4 ov;
        ov.x = (x0 - mean) * rstd * Lg[l * 4]     + Lb[l * 4];
        ov.y = (x1 - mean) * rstd * Lg[l * 4 + 1] + Lb[l * 4 + 1];
        ov.z = (x2 - mean) * rstd * Lg[l * 4 + 2] + Lb[l * 4 + 2];
        ov.w = (x3 - mean) * rstd * Lg[l * 4 + 3] + Lb[l * 4 + 3];
        *(float4*)&out[(r0 + row) * HIDD + l * 4] = ov;
    }
}

// ---------------- host ----------------

extern "C" void kernel_launch(void* const* d_in, const int* in_sizes, int n_in,
                              void* d_out, int out_size, void* d_ws, size_t ws_size,
                              hipStream_t stream) {
    const float* src  = (const float*)d_in[0];
    const float* tgt  = (const float*)d_in[1];
    const float* pos  = (const float*)d_in[2];
    const int*   ei   = (const int*)d_in[3];
    const float* Wq   = (const float*)d_in[4];  const float* bq  = (const float*)d_in[5];
    const float* Wk   = (const float*)d_in[6];  const float* bk  = (const float*)d_in[7];
    const float* Wv   = (const float*)d_in[8];  const float* bv  = (const float*)d_in[9];
    const float* gw1  = (const float*)d_in[10]; const float* gb1 = (const float*)d_in[11];
    const float* gw2  = (const float*)d_in[12]; const float* gb2 = (const float*)d_in[13];
    const float* tw1  = (const float*)d_in[14]; const float* tb1 = (const float*)d_in[15];
    const float* tw2  = (const float*)d_in[16]; const float* tb2 = (const float*)d_in[17];
    const float* gaw1 = (const float*)d_in[18]; const float* gab1= (const float*)d_in[19];
    const float* gaw2 = (const float*)d_in[20]; const float* gab2= (const float*)d_in[21];
    const float* Wo   = (const float*)d_in[22]; const float* bo  = (const float*)d_in[23];
    const float* lng  = (const float*)d_in[24]; const float* lnb = (const float*)d_in[25];
    int E = in_sizes[3] / 2;

    char* w = (char*)d_ws;
    unsigned* p0   = (unsigned*)w; w += NN * NW * 4;        // zeroed (adj rows)
    float* glog    = (float*)w;    w += NN * 2 * 4;         // zeroed (contiguous)
    unsigned* p1   = (unsigned*)w; w += NN * NW * 4;
    unsigned short* src_bf = (unsigned short*)w; w += NN * HIDD * 2;
    unsigned short* tgt_bf = (unsigned short*)w; w += NN * HIDD * 2;
    unsigned short* gateA  = (unsigned short*)w; w += NN * 512 * 2;
    unsigned short* WqT    = (unsigned short*)w; w += HIDD * HIDD * 2;
    unsigned short* WkT    = (unsigned short*)w; w += HIDD * HIDD * 2;
    unsigned short* WvT    = (unsigned short*)w; w += HIDD * HIDD * 2;
    unsigned short* WoT    = (unsigned short*)w; w += HIDD * HIDD * 2;
    unsigned short* gaw1T  = (unsigned short*)w; w += 1024 * 512 * 2;
    unsigned short* q_bf   = (unsigned short*)w; w += NN * HIDD * 2;
    unsigned short* k_bf   = (unsigned short*)w; w += NN * HIDD * 2;
    unsigned short* vT     = (unsigned short*)w; w += HIDD * NN * 2;   // [256][1024]
    float* t01  = (float*)w; w += 256;
    unsigned* gtab = (unsigned*)w; w += 512 * 16;               // 8 KB geo table
    float* Opart = (float*)w; w += (long)NCH * NN * HIDD * 4;   // 8 MB
    float* mlb   = (float*)w; w += (long)NCH * NN * NH * 2 * 4; // 512 KB

    int nsc = (E + 255) / 256;

    // zero p0 (adj rows) + glog (contiguous)
    hipMemsetAsync(p0, 0, NN * NW * 4 + NN * 2 * 4, stream);

    prep_kernel<<<1027 + nsc, 256, 0, stream>>>(src, tgt, Wq, Wk, Wv, Wo, gaw1,
                                                tw1, tb1, tw2, tb2,
                                                gw1, gb1, gw2, gb2, ei, E,
                                                src_bf, tgt_bf, gateA,
                                                WqT, WkT, WvT, WoT, gaw1T,
                                                t01, gtab, p0);

    // all 3 path iterations, row-local against static adjacency; result in p1
    path3_kernel<<<NN / 4, 256, 0, stream>>>(p0, p1);

    proj_kernel<<<448, 256, 0, stream>>>(src_bf, tgt_bf, gateA, WqT, WkT, WvT, gaw1T,
                                         bq, bk, bv, gab1, gaw2,
                                         q_bf, k_bf, vT, glog);

    flash_kernel<<<dim3(NCH, 64), 512, 0, stream>>>(q_bf, k_bf, vT, pos, glog, gab2,
                                                    p1, t01, gtab, Opart, mlb);

    wo_ln_kernel<<<NN / 16, 512, 0, stream>>>(Opart, mlb, WoT, bo, src, lng, lnb,
                                              (float*)d_out);
}

// Round 5
// 157.684 us; speedup vs baseline: 1.8054x; 1.1361x over previous
//
#include <hip/hip_runtime.h>
#include <math.h>

#define NN   1024
#define HIDD 256
#define NH   8
#define NW   32   // 1024 bits / 32 per word
#define MC   128  // flash m-chunk size
#define NCH  8    // flash chunks
#define GS   130  // geo2 row stride (dwords) — quad banks 0/8/16/24, 2-way free
#define PSW  136  // Pb row stride (shorts)

typedef __attribute__((ext_vector_type(8))) short short8;
typedef __attribute__((ext_vector_type(4))) float f32x4;

__device__ __forceinline__ float silu_f(float x) {
    // x * sigmoid(x); v_rcp instead of full-precision div chain (~1ulp rel err)
    return x * __builtin_amdgcn_rcpf(1.0f + __expf(-x));
}
__device__ __forceinline__ unsigned short f2bf(float x) {
    unsigned b = __float_as_uint(x);
    return (unsigned short)((b + 0x7FFFu + ((b >> 16) & 1u)) >> 16);
}
__device__ __forceinline__ float bf2f(unsigned u) {
    return __uint_as_float(u << 16);
}

// ---------------- fused prep ----------------
// b <  256 : feature f32->bf16 conversion, 8 elems/thread, vectorized
// b < 1024 : weight transposes (QKVO 256, gate W1 512)
// b == 1024: topo 2-entry table (path bit 0/1)
// b == 1025/1026: geo MLP table — 512 knots over dist in [0,16], bf16 packed
// b >= 1027: edge scatter -> row bitsets

__global__ __launch_bounds__(256)
void prep_kernel(const float* __restrict__ src, const float* __restrict__ tgt,
                 const float* __restrict__ Wq, const float* __restrict__ Wk,
                 const float* __restrict__ Wv, const float* __restrict__ Wo,
                 const float* __restrict__ gaw1,
                 const float* __restrict__ tw1, const float* __restrict__ tb1,
                 const float* __restrict__ tw2, const float* __restrict__ tb2,
                 const float* __restrict__ gw1, const float* __restrict__ gb1,
                 const float* __restrict__ gw2, const float* __restrict__ gb2,
                 const int* __restrict__ ei, int E,
                 unsigned short* __restrict__ src_bf, unsigned short* __restrict__ tgt_bf,
                 unsigned short* __restrict__ WqT, unsigned short* __restrict__ WkT,
                 unsigned short* __restrict__ WvT, unsigned short* __restrict__ WoT,
                 unsigned short* __restrict__ gaw1T,
                 float* __restrict__ t01, unsigned* __restrict__ gtab,
                 unsigned* __restrict__ prow) {
    __shared__ float tile[32][33];
    int b = blockIdx.x, t = threadIdx.x;
    if (b < 256) {
        int idx = b * 256 + t;          // 65536 threads, 8 elems each
        int n = idx >> 6, g = idx & 63;
        int j = g * 8;
        const float* base = (g < 32) ? (src + n * 256 + j)
                                     : (tgt + n * 256 + j - 256);
        float4 v0 = *(const float4*)base;
        float4 v1 = *(const float4*)(base + 4);
        unsigned short u[8] = {f2bf(v0.x), f2bf(v0.y), f2bf(v0.z), f2bf(v0.w),
                               f2bf(v1.x), f2bf(v1.y), f2bf(v1.z), f2bf(v1.w)};
        int4 pk = *(int4*)u;
        if (g < 32) *(int4*)&src_bf[n * 256 + j] = pk;
        else        *(int4*)&tgt_bf[n * 256 + j - 256] = pk;
    } else if (b < 1024) {
        int b2 = b - 256;
        const float* W; unsigned short* Wt; int Kd, Nd, n0, k0;
        if (b2 < 256) {
            int which = b2 >> 6, tl = b2 & 63;
            W  = (which == 0) ? Wq : (which == 1) ? Wk : (which == 2) ? Wv : Wo;
            Wt = (which == 0) ? WqT : (which == 1) ? WkT : (which == 2) ? WvT : WoT;
            Kd = 256; Nd = 256;
            n0 = (tl & 7) * 32; k0 = (tl >> 3) * 32;
        } else {
            int b3 = b2 - 256;
            W = gaw1; Wt = gaw1T; Kd = 512; Nd = 1024;
            n0 = (b3 & 31) * 32; k0 = (b3 >> 5) * 32;
        }
        int tx = t & 31, ty = t >> 5;
        #pragma unroll
        for (int p = 0; p < 4; ++p)
            tile[ty + p * 8][tx] = W[(k0 + ty + p * 8) * (long)Nd + n0 + tx];
        __syncthreads();
        #pragma unroll
        for (int p = 0; p < 4; ++p)
            Wt[(n0 + ty + p * 8) * (long)Kd + k0 + tx] = f2bf(tile[tx][ty + p * 8]);
    } else if (b == 1024) {
        if (t < 16) {
            int h = t & 7;
            float x = (t >> 3) ? 1.0f : 0.0f;
            float acc = tb2[h];
            for (int c = 0; c < 32; ++c)
                acc += silu_f(x * tw1[c] + tb1[c]) * tw2[c * 8 + h];
            t01[t] = acc;
        }
    } else if (b == 1025 || b == 1026) {
        int e = (b - 1025) * 256 + t;   // knot 0..511, dist = e/32
        float d = (float)e * 0.03125f;
        float go[8];
        #pragma unroll
        for (int h = 0; h < 8; ++h) go[h] = gb2[h];
        for (int c = 0; c < 32; ++c) {
            float hh = silu_f(d * gw1[c] + gb1[c]);
            #pragma unroll
            for (int h = 0; h < 8; ++h) go[h] += hh * gw2[c * 8 + h];
        }
        #pragma unroll
        for (int h2 = 0; h2 < 4; ++h2)
            gtab[e * 4 + h2] = (unsigned)f2bf(go[2 * h2]) |
                               ((unsigned)f2bf(go[2 * h2 + 1]) << 16);
    } else {
        int e = (b - 1027) * 256 + t;
        if (e < E) {
            int r = ei[e], c = ei[E + e];
            if ((unsigned)r < NN && (unsigned)c < NN)
                atomicOr(&prow[r * NW + (c >> 5)], 1u << (c & 31));
        }
    }
}

// ---------------- shared MFMA 64x64 tile (register-prefetch pipeline) -------

__device__ __forceinline__ void mfma_tile64(const unsigned short* __restrict__ A,
                                            const unsigned short* __restrict__ Bt,
                                            int K, int i0, int j0, int t,
                                            f32x4 acc[2][2],
                                            unsigned short* As, unsigned short* Bs) {
    int l = t & 63, w = t >> 6;
    int wi = w >> 1, wj = w & 1;
    int quad = l >> 4, lj = l & 15;
    int sr = t >> 2, skp = (t & 3) * 8;
    f32x4 z = {0.f, 0.f, 0.f, 0.f};
    acc[0][0] = z; acc[0][1] = z; acc[1][0] = z; acc[1][1] = z;
    const unsigned short* pa = &A[(i0 + sr) * (long)K + skp];
    const unsigned short* pb = &Bt[(j0 + sr) * (long)K + skp];
    int4 ra = *(const int4*)pa;
    int4 rb = *(const int4*)pb;
    for (int k0 = 0; k0 < K; k0 += 32) {
        *(int4*)&As[sr * 32 + skp] = ra;
        *(int4*)&Bs[sr * 32 + skp] = rb;
        __syncthreads();
        if (k0 + 32 < K) {              // prefetch next tile; hides under MFMAs
            ra = *(const int4*)(pa + k0 + 32);
            rb = *(const int4*)(pb + k0 + 32);
        }
        short8 a0 = *(short8*)&As[(wi * 32 + lj) * 32 + quad * 8];
        short8 a1 = *(short8*)&As[(wi * 32 + 16 + lj) * 32 + quad * 8];
        short8 b0 = *(short8*)&Bs[(wj * 32 + lj) * 32 + quad * 8];
        short8 b1 = *(short8*)&Bs[(wj * 32 + 16 + lj) * 32 + quad * 8];
        acc[0][0] = __builtin_amdgcn_mfma_f32_16x16x32_bf16(a0, b0, acc[0][0], 0, 0, 0);
        acc[0][1] = __builtin_amdgcn_mfma_f32_16x16x32_bf16(a0, b1, acc[0][1], 0, 0, 0);
        acc[1][0] = __builtin_amdgcn_mfma_f32_16x16x32_bf16(a1, b0, acc[1][0], 0, 0, 0);
        acc[1][1] = __builtin_amdgcn_mfma_f32_16x16x32_bf16(a1, b1, acc[1][1], 0, 0, 0);
        __syncthreads();
    }
}

// Gate variant: A = concat(src_bf, tgt_bf) read directly (no gateA buffer).
// K = 512; BK=32 tiles never straddle k=256, so pick the source per k-tile.

__device__ __forceinline__ void mfma_tile64_split(const unsigned short* __restrict__ Asrc,
                                                  const unsigned short* __restrict__ Atgt,
                                                  const unsigned short* __restrict__ Bt,
                                                  int i0, int j0, int t,
                                                  f32x4 acc[2][2],
                                                  unsigned short* As, unsigned short* Bs) {
    int l = t & 63, w = t >> 6;
    int wi = w >> 1, wj = w & 1;
    int quad = l >> 4, lj = l & 15;
    int sr = t >> 2, skp = (t & 3) * 8;
    f32x4 z = {0.f, 0.f, 0.f, 0.f};
    acc[0][0] = z; acc[0][1] = z; acc[1][0] = z; acc[1][1] = z;
    const unsigned short* pb = &Bt[(j0 + sr) * 512L + skp];
    int4 ra = *(const int4*)&Asrc[(i0 + sr) * 256 + skp];
    int4 rb = *(const int4*)pb;
    for (int k0 = 0; k0 < 512; k0 += 32) {
        *(int4*)&As[sr * 32 + skp] = ra;
        *(int4*)&Bs[sr * 32 + skp] = rb;
        __syncthreads();
        if (k0 + 32 < 512) {
            int kn = k0 + 32;
            ra = (kn < 256)
               ? *(const int4*)&Asrc[(i0 + sr) * 256 + kn + skp]
               : *(const int4*)&Atgt[(i0 + sr) * 256 + (kn - 256) + skp];
            rb = *(const int4*)(pb + kn);
        }
        short8 a0 = *(short8*)&As[(wi * 32 + lj) * 32 + quad * 8];
        short8 a1 = *(short8*)&As[(wi * 32 + 16 + lj) * 32 + quad * 8];
        short8 b0 = *(short8*)&Bs[(wj * 32 + lj) * 32 + quad * 8];
        short8 b1 = *(short8*)&Bs[(wj * 32 + 16 + lj) * 32 + quad * 8];
        acc[0][0] = __builtin_amdgcn_mfma_f32_16x16x32_bf16(a0, b0, acc[0][0], 0, 0, 0);
        acc[0][1] = __builtin_amdgcn_mfma_f32_16x16x32_bf16(a0, b1, acc[0][1], 0, 0, 0);
        acc[1][0] = __builtin_amdgcn_mfma_f32_16x16x32_bf16(a1, b0, acc[1][0], 0, 0, 0);
        acc[1][1] = __builtin_amdgcn_mfma_f32_16x16x32_bf16(a1, b1, acc[1][1], 0, 0, 0);
        __syncthreads();
    }
}

// ---------------- projections + path (fused) ----------------
// b <  192: QKV GEMMs
// b <  448: gate hidden w/ fused logits
// b >= 448: path propagation (3 iters, row-local vs static adjacency) —
//           independent sibling of the GEMMs in the DAG; fused to save a launch.

__global__ __launch_bounds__(256)
void proj_kernel(const unsigned short* __restrict__ src_bf,
                 const unsigned short* __restrict__ tgt_bf,
                 const unsigned short* __restrict__ WqT,
                 const unsigned short* __restrict__ WkT,
                 const unsigned short* __restrict__ WvT,
                 const unsigned short* __restrict__ gaw1T,
                 const float* __restrict__ bq, const float* __restrict__ bk,
                 const float* __restrict__ bv, const float* __restrict__ gab1,
                 const float* __restrict__ gaw2,
                 unsigned short* __restrict__ q_bf, unsigned short* __restrict__ k_bf,
                 unsigned short* __restrict__ vT, float* __restrict__ glog,
                 const unsigned* __restrict__ arow, unsigned* __restrict__ pout) {
    __shared__ unsigned short As[64 * 32];
    __shared__ unsigned short Bs[64 * 32];
    int b = blockIdx.x, t = threadIdx.x;
    int l = t & 63, w = t >> 6, wi = w >> 1, wjq = w & 1, quad = l >> 4, lj = l & 15;
    f32x4 acc[2][2];
    if (b < 192) {
        int z = b >> 6, rem = b & 63;
        int j0 = (rem & 3) * 64, i0 = (rem >> 2) * 64;
        const unsigned short* A  = (z == 0) ? src_bf : tgt_bf;
        const unsigned short* Bt = (z == 0) ? WqT : (z == 1) ? WkT : WvT;
        const float* bias        = (z == 0) ? bq : (z == 1) ? bk : bv;
        mfma_tile64(A, Bt, HIDD, i0, j0, t, acc, As, Bs);
        #pragma unroll
        for (int rg = 0; rg < 2; ++rg)
            #pragma unroll
            for (int cg = 0; cg < 2; ++cg) {
                int col  = j0 + wjq * 32 + cg * 16 + lj;
                int row0 = i0 + wi * 32 + rg * 16 + quad * 4;
                float bb = bias[col];
                if (z < 2) {
                    unsigned short* obf = (z == 0) ? q_bf : k_bf;
                    #pragma unroll
                    for (int r = 0; r < 4; ++r)
                        obf[(row0 + r) * HIDD + col] = f2bf(acc[rg][cg][r] + bb);
                } else {
                    unsigned short vv[4];
                    #pragma unroll
                    for (int r = 0; r < 4; ++r) vv[r] = f2bf(acc[rg][cg][r] + bb);
                    *(int2*)&vT[col * NN + row0] = *(int2*)vv;
                }
            }
    } else if (b < 448) {
        int b2 = b - 192;
        int j0 = (b2 & 15) * 64, i0 = (b2 >> 4) * 64;
        mfma_tile64_split(src_bf, tgt_bf, gaw1T, i0, j0, t, acc, As, Bs);
        float p[8][2];
        #pragma unroll
        for (int s = 0; s < 8; ++s) { p[s][0] = 0.f; p[s][1] = 0.f; }
        #pragma unroll
        for (int cg = 0; cg < 2; ++cg) {
            int col = j0 + wjq * 32 + cg * 16 + lj;
            float w20 = gaw2[col * 2], w21 = gaw2[col * 2 + 1];
            float bb = gab1[col];
            #pragma unroll
            for (int rg = 0; rg < 2; ++rg)
                #pragma unroll
                for (int r = 0; r < 4; ++r) {
                    float hv = silu_f(acc[rg][cg][r] + bb);
                    p[rg * 4 + r][0] += hv * w20;
                    p[rg * 4 + r][1] += hv * w21;
                }
        }
        #pragma unroll
        for (int off = 1; off < 16; off <<= 1)
            #pragma unroll
            for (int s = 0; s < 8; ++s) {
                p[s][0] += __shfl_xor(p[s][0], off, 64);
                p[s][1] += __shfl_xor(p[s][1], off, 64);
            }
        if (lj == 0) {
            #pragma unroll
            for (int rg = 0; rg < 2; ++rg)
                #pragma unroll
                for (int r = 0; r < 4; ++r) {
                    int row = i0 + wi * 32 + rg * 16 + quad * 4 + r;
                    atomicAdd(&glog[row * 2],     p[rg * 4 + r][0]);
                    atomicAdd(&glog[row * 2 + 1], p[rg * 4 + r][1]);
                }
        }
    } else {
        // path: out_row_i = row_i AND (OR over set bits k of row_i of adj_row_k);
        // adj static -> 3 iterations are row-local (rows only sparsify).
        int wj = l & 31;
        int i  = (b - 448) * 4 + (t >> 6);
        unsigned r = arow[i * NW + wj];
        #pragma unroll
        for (int it = 0; it < 3; ++it) {
            unsigned acc2 = 0u;
            for (int w2 = 0; w2 < NW; ++w2) {
                unsigned m = __shfl(r, w2, 64);   // wave-uniform word
                while (m) {
                    int bb = __ffs(m) - 1;
                    m &= m - 1;
                    acc2 |= arow[(((w2 << 5) | bb)) * NW + wj];
                }
            }
            r &= acc2;
        }
        if (l < 32) pout[i * NW + wj] = r;
    }
}

// ---------------- flash attention v2 ----------------
// grid (8 m-chunks of 128, 64 row-tiles of 16). 512 threads = 8 waves; wave w
// handles head h=w fully independently. Geo bias via 512-knot lerp table.

__global__ __launch_bounds__(512)
void flash_kernel(const unsigned short* __restrict__ qbf,
                  const unsigned short* __restrict__ kbf,
                  const unsigned short* __restrict__ vT,
                  const float* __restrict__ pos, const float* __restrict__ glog,
                  const float* __restrict__ gab2,
                  const unsigned* __restrict__ pbits, const float* __restrict__ t01,
                  const unsigned* __restrict__ gtab,
                  float* __restrict__ Opart, float* __restrict__ ml) {
    __shared__ unsigned geo2[4 * 16 * GS];      // 33.3 KB [h/2][i][j]
    __shared__ unsigned short Pb[8 * 16 * PSW]; // 34.8 KB, wave-private eighths
    __shared__ unsigned tabs[512 * 4];          // 8 KB geo lerp table
    __shared__ float posA[48], posB[384];
    __shared__ unsigned prowL[64];              // 16 rows x 4 words
    __shared__ float g01[32];
    __shared__ float t01s[16];
    int t  = threadIdx.x;
    int bx = blockIdx.x;               // m-chunk
    int n0 = blockIdx.y * 16;
    int mbase = bx * MC;
    *(uint4*)&tabs[t * 4] = *(const uint4*)&gtab[t * 4];
    if (t < 384) posB[t] = pos[mbase * 3 + t];
    if (t < 48)  posA[t] = pos[n0 * 3 + t];
    if (t < 64)  prowL[t] = pbits[(n0 + (t >> 2)) * NW + bx * 4 + (t & 3)];
    if (t < 16) {
        float L0 = glog[(n0 + t) * 2]     + gab2[0];
        float L1 = glog[(n0 + t) * 2 + 1] + gab2[1];
        float mx = fmaxf(L0, L1);
        float e0 = __expf(L0 - mx), e1 = __expf(L1 - mx);
        float inv = 1.0f / (e0 + e1);
        g01[2 * t]     = e0 * inv;
        g01[2 * t + 1] = e1 * inv;
    }
    if (t < 16) t01s[t] = t01[t];
    __syncthreads();

    // phase 1: dist + table lerp, 2048 pairs, 4 per thread
    for (int pp = 0; pp < 4; ++pp) {
        int p = pp * 512 + t;
        int i = p >> 7, j = p & (MC - 1);
        float dx = posA[i * 3]     - posB[j * 3];
        float dy = posA[i * 3 + 1] - posB[j * 3 + 1];
        float dz = posA[i * 3 + 2] - posB[j * 3 + 2];
        float dist = sqrtf(fmaxf(dx * dx + dy * dy + dz * dz, 1e-12f));
        float fx = fminf(dist * 32.0f, 510.999f);
        int ix = (int)fx;
        float fr = fx - (float)ix;
        const unsigned* tp = &tabs[ix * 4];
        #pragma unroll
        for (int h2 = 0; h2 < 4; ++h2) {
            unsigned ta = tp[h2], tb = tp[h2 + 4];
            float a0 = bf2f(ta & 0xffffu), a1 = bf2f(ta >> 16);
            float b0 = bf2f(tb & 0xffffu), b1 = bf2f(tb >> 16);
            geo2[h2 * 16 * GS + i * GS + j] =
                (unsigned)f2bf(a0 + (b0 - a0) * fr) |
                ((unsigned)f2bf(a1 + (b1 - a1) * fr) << 16);
        }
    }
    __syncthreads();

    int l = t & 63, w = t >> 6, quad = l >> 4, lj = l & 15;
    int h = w;                          // one head per wave
    unsigned short* Pw = &Pb[w * 16 * PSW];
    const float scale = 0.17677669529663687f;  // 1/sqrt(32)
    f32x4 z = {0.f, 0.f, 0.f, 0.f};

    // QK: 8 col-tiles of 16
    short8 a = *(const short8*)&qbf[(n0 + lj) * HIDD + h * 32 + quad * 8];
    f32x4 acc[8];
    #pragma unroll
    for (int tl = 0; tl < 8; ++tl) {
        short8 bfr = *(const short8*)&kbf[(mbase + tl * 16 + lj) * HIDD +
                                          h * 32 + quad * 8];
        acc[tl] = __builtin_amdgcn_mfma_f32_16x16x32_bf16(a, bfr, z, 0, 0, 0);
    }
    // bias add: row i=quad*4+r, col j=tl*16+lj (hoisted scalars, same math)
    float t0h = t01s[h], t1h = t01s[8 + h];
    float g0r[4], g1r[4];
    #pragma unroll
    for (int r = 0; r < 4; ++r) {
        g0r[r] = g01[2 * (quad * 4 + r)];
        g1r[r] = g01[2 * (quad * 4 + r) + 1];
    }
    #pragma unroll
    for (int tl = 0; tl < 8; ++tl) {
        int j = tl * 16 + lj;
        #pragma unroll
        for (int r = 0; r < 4; ++r) {
            int i = quad * 4 + r;
            unsigned gv = geo2[(h >> 1) * 16 * GS + i * GS + j];
            float geo_v = __uint_as_float((h & 1) ? (gv & 0xffff0000u) : (gv << 16));
            unsigned bit = (prowL[i * 4 + (j >> 5)] >> (j & 31)) & 1u;
            float tv = bit ? t1h : t0h;
            acc[tl][r] = acc[tl][r] * scale + g0r[r] * geo_v + g1r[r] * tv;
        }
    }
    // wave-internal row max (quads own disjoint rows; reduce over 16 lj)
    float mr[4];
    #pragma unroll
    for (int r = 0; r < 4; ++r) {
        float m01 = fmaxf(fmaxf(acc[0][r], acc[1][r]), fmaxf(acc[2][r], acc[3][r]));
        float m23 = fmaxf(fmaxf(acc[4][r], acc[5][r]), fmaxf(acc[6][r], acc[7][r]));
        mr[r] = fmaxf(m01, m23);
    }
    #pragma unroll
    for (int off = 1; off < 16; off <<= 1)
        #pragma unroll
        for (int r = 0; r < 4; ++r) mr[r] = fmaxf(mr[r], __shfl_xor(mr[r], off, 64));
    // exp, P -> wave-private LDS (A-layout), row sums
    float sm[4] = {0.f, 0.f, 0.f, 0.f};
    #pragma unroll
    for (int tl = 0; tl < 8; ++tl) {
        int j = tl * 16 + lj;
        #pragma unroll
        for (int r = 0; r < 4; ++r) {
            float e = __expf(acc[tl][r] - mr[r]);
            Pw[(quad * 4 + r) * PSW + j] = f2bf(e);
            sm[r] += e;
        }
    }
    #pragma unroll
    for (int off = 1; off < 16; off <<= 1)
        #pragma unroll
        for (int r = 0; r < 4; ++r) sm[r] += __shfl_xor(sm[r], off, 64);
    if (lj == 0) {
        #pragma unroll
        for (int r = 0; r < 4; ++r) {
            int i = quad * 4 + r;
            int base = ((bx * NN + n0 + i) * NH + h) * 2;
            ml[base] = mr[r]; ml[base + 1] = sm[r];
        }
    }
    // PV: K=128, 2 d-tiles; same-wave DS ordering makes this safe w/o barrier
    f32x4 o[2] = {z, z};
    #pragma unroll
    for (int ks = 0; ks < 4; ++ks) {
        short8 aP = *(short8*)&Pw[lj * PSW + ks * 32 + quad * 8];
        #pragma unroll
        for (int dt = 0; dt < 2; ++dt) {
            short8 bV = *(const short8*)&vT[(h * 32 + dt * 16 + lj) * NN +
                                            mbase + ks * 32 + quad * 8];
            o[dt] = __builtin_amdgcn_mfma_f32_16x16x32_bf16(aP, bV, o[dt], 0, 0, 0);
        }
    }
    #pragma unroll
    for (int dt = 0; dt < 2; ++dt)
        #pragma unroll
        for (int r = 0; r < 4; ++r)
            Opart[((long)(bx * NN + n0 + quad * 4 + r)) * HIDD +
                  h * 32 + dt * 16 + lj] = o[dt][r];
}

// ---------------- combine + Wo projection + residual + LayerNorm ----------------
// 128 blocks x 8 rows (latency-bound -> double block parallelism). MFMA A rows
// 8..15 zero-padded; LN = 1 row/wave. Per-row math identical to before.

#define PS 264

__global__ __launch_bounds__(512)
void wo_ln_kernel(const float* __restrict__ Opart, const float* __restrict__ ml,
                  const unsigned short* __restrict__ WoT,
                  const float* __restrict__ bo, const float* __restrict__ xres,
                  const float* __restrict__ lng, const float* __restrict__ lnb,
                  float* __restrict__ out) {
    __shared__ unsigned short Asm[16 * PS];
    __shared__ float Osm[8][260];
    __shared__ float Lg[256], Lb[256];
    __shared__ float wc[8][NH][NCH];
    __shared__ float invl[8][NH];
    int t = threadIdx.x;
    int r0 = blockIdx.x * 8;
    if (t < 256) { Lg[t] = lng[t]; Lb[t] = lnb[t]; }
    if (t < 64) {
        int r = t >> 3, h = t & 7;
        float mm[NCH], ll[NCH];
        float M = -1e30f;
        #pragma unroll
        for (int ch = 0; ch < NCH; ++ch) {
            int base = ((ch * NN + r0 + r) * NH + h) * 2;
            mm[ch] = ml[base]; ll[ch] = ml[base + 1];
            M = fmaxf(M, mm[ch]);
        }
        float lt = 0.f;
        #pragma unroll
        for (int ch = 0; ch < NCH; ++ch) {
            float wv = __expf(mm[ch] - M);
            wc[r][h][ch] = wv;
            lt += wv * ll[ch];
        }
        invl[r][h] = 1.0f / lt;
    }
    __syncthreads();
    {
        int r = t >> 6, c0 = t & 63;    // 8 rows x 64 cols per pass, 4 passes
        #pragma unroll
        for (int cc = 0; cc < 4; ++cc) {
            int c = cc * 64 + c0;
            int h = c >> 5;
            float v = 0.f;
            #pragma unroll
            for (int ch = 0; ch < NCH; ++ch)
                v += wc[r][h][ch] * Opart[((long)(ch * NN + r0 + r)) * HIDD + c];
            Asm[r * PS + c] = f2bf(v * invl[r][h]);
            Asm[(r + 8) * PS + c] = 0;  // zero-pad MFMA A rows 8..15
        }
    }
    __syncthreads();
    int l = t & 63, w = t >> 6, quad = l >> 4, lj = l & 15;
    f32x4 z = {0.f, 0.f, 0.f, 0.f};
    f32x4 acc[2] = {z, z};
    for (int ks = 0; ks < 8; ++ks) {
        short8 a = *(short8*)&Asm[lj * PS + ks * 32 + quad * 8];
        #pragma unroll
        for (int nt = 0; nt < 2; ++nt) {
            int col = w * 32 + nt * 16 + lj;
            short8 bfr = *(const short8*)&WoT[col * HIDD + ks * 32 + quad * 8];
            acc[nt] = __builtin_amdgcn_mfma_f32_16x16x32_bf16(a, bfr, acc[nt], 0, 0, 0);
        }
    }
    #pragma unroll
    for (int nt = 0; nt < 2; ++nt) {
        int col = w * 32 + nt * 16 + lj;
        float bb = bo[col];
        #pragma unroll
        for (int r = 0; r < 4; ++r) {
            int row = quad * 4 + r;
            if (row < 8) Osm[row][col] = acc[nt][r] + bb;
        }
    }
    __syncthreads();
    {
        int row = w;                    // 1 row per wave
        float4 o  = *(float4*)&Osm[row][l * 4];
        float4 s4 = *(const float4*)&xres[(r0 + row) * HIDD + l * 4];
        float x0 = o.x + s4.x, x1 = o.y + s4.y, x2 = o.z + s4.z, x3 = o.w + s4.w;
        float sum = x0 + x1 + x2 + x3;
        float ss  = x0 * x0 + x1 * x1 + x2 * x2 + x3 * x3;
        #pragma unroll
        for (int off = 32; off > 0; off >>= 1) {
            sum += __shfl_xor(sum, off, 64);
            ss  += __shfl_xor(ss,  off, 64);
        }
        float mean = sum * (1.0f / HIDD);
        float var  = ss * (1.0f / HIDD) - mean * mean;
        float rstd = rsqrtf(var + 1e-5f);
        float4 ov;
        ov.x = (x0 - mean) * rstd * Lg[l * 4]     + Lb[l * 4];
        ov.y = (x1 - mean) * rstd * Lg[l * 4 + 1] + Lb[l * 4 + 1];
        ov.z = (x2 - mean) * rstd * Lg[l * 4 + 2] + Lb[l * 4 + 2];
        ov.w = (x3 - mean) * rstd * Lg[l * 4 + 3] + Lb[l * 4 + 3];
        *(float4*)&out[(r0 + row) * HIDD + l * 4] = ov;
    }
}

// ---------------- host ----------------

extern "C" void kernel_launch(void* const* d_in, const int* in_sizes, int n_in,
                              void* d_out, int out_size, void* d_ws, size_t ws_size,
                              hipStream_t stream) {
    const float* src  = (const float*)d_in[0];
    const float* tgt  = (const float*)d_in[1];
    const float* pos  = (const float*)d_in[2];
    const int*   ei   = (const int*)d_in[3];
    const float* Wq   = (const float*)d_in[4];  const float* bq  = (const float*)d_in[5];
    const float* Wk   = (const float*)d_in[6];  const float* bk  = (const float*)d_in[7];
    const float* Wv   = (const float*)d_in[8];  const float* bv  = (const float*)d_in[9];
    const float* gw1  = (const float*)d_in[10]; const float* gb1 = (const float*)d_in[11];
    const float* gw2  = (const float*)d_in[12]; const float* gb2 = (const float*)d_in[13];
    const float* tw1  = (const float*)d_in[14]; const float* tb1 = (const float*)d_in[15];
    const float* tw2  = (const float*)d_in[16]; const float* tb2 = (const float*)d_in[17];
    const float* gaw1 = (const float*)d_in[18]; const float* gab1= (const float*)d_in[19];
    const float* gaw2 = (const float*)d_in[20]; const float* gab2= (const float*)d_in[21];
    const float* Wo   = (const float*)d_in[22]; const float* bo  = (const float*)d_in[23];
    const float* lng  = (const float*)d_in[24]; const float* lnb = (const float*)d_in[25];
    int E = in_sizes[3] / 2;

    char* w = (char*)d_ws;
    unsigned* p0   = (unsigned*)w; w += NN * NW * 4;        // zeroed (adj rows)
    float* glog    = (float*)w;    w += NN * 2 * 4;         // zeroed (contiguous)
    unsigned* p1   = (unsigned*)w; w += NN * NW * 4;
    unsigned short* src_bf = (unsigned short*)w; w += NN * HIDD * 2;
    unsigned short* tgt_bf = (unsigned short*)w; w += NN * HIDD * 2;
    unsigned short* WqT    = (unsigned short*)w; w += HIDD * HIDD * 2;
    unsigned short* WkT    = (unsigned short*)w; w += HIDD * HIDD * 2;
    unsigned short* WvT    = (unsigned short*)w; w += HIDD * HIDD * 2;
    unsigned short* WoT    = (unsigned short*)w; w += HIDD * HIDD * 2;
    unsigned short* gaw1T  = (unsigned short*)w; w += 1024 * 512 * 2;
    unsigned short* q_bf   = (unsigned short*)w; w += NN * HIDD * 2;
    unsigned short* k_bf   = (unsigned short*)w; w += NN * HIDD * 2;
    unsigned short* vT     = (unsigned short*)w; w += HIDD * NN * 2;   // [256][1024]
    float* t01  = (float*)w; w += 256;
    unsigned* gtab = (unsigned*)w; w += 512 * 16;               // 8 KB geo table
    float* Opart = (float*)w; w += (long)NCH * NN * HIDD * 4;   // 8 MB
    float* mlb   = (float*)w; w += (long)NCH * NN * NH * 2 * 4; // 512 KB

    int nsc = (E + 255) / 256;

    // zero p0 (adj rows) + glog (contiguous)
    hipMemsetAsync(p0, 0, NN * NW * 4 + NN * 2 * 4, stream);

    prep_kernel<<<1027 + nsc, 256, 0, stream>>>(src, tgt, Wq, Wk, Wv, Wo, gaw1,
                                                tw1, tb1, tw2, tb2,
                                                gw1, gb1, gw2, gb2, ei, E,
                                                src_bf, tgt_bf,
                                                WqT, WkT, WvT, WoT, gaw1T,
                                                t01, gtab, p0);

    // QKV + gate GEMMs + path propagation (independent siblings) in one launch
    proj_kernel<<<704, 256, 0, stream>>>(src_bf, tgt_bf, WqT, WkT, WvT, gaw1T,
                                         bq, bk, bv, gab1, gaw2,
                                         q_bf, k_bf, vT, glog, p0, p1);

    flash_kernel<<<dim3(NCH, 64), 512, 0, stream>>>(q_bf, k_bf, vT, pos, glog, gab2,
                                                    p1, t01, gtab, Opart, mlb);

    wo_ln_kernel<<<NN / 8, 512, 0, stream>>>(Opart, mlb, WoT, bo, src, lng, lnb,
                                             (float*)d_out);
}